// Round 14
// baseline (362.796 us; speedup 1.0000x reference)
//
#include <hip/hip_runtime.h>
#include <math.h>
#include <stdint.h>

#define HH 512
#define WW 512
#define BB 64
#define NP 13860
#define WPR 16                       // 32-bit words per image row
#define IMG_WORDS (BB * HH * WPR)    // 2 MB bit-image for all batches

typedef float vfloat4 __attribute__((ext_vector_type(4)));

struct GaussW { float g[9]; };

__device__ __forceinline__ int reflect_idx(int i) {
    if (i < 0) i = -i;
    if (i > 511) i = 1022 - i;
    return i;
}

// ----------------------------------------------------------------- zero ----
__global__ __launch_bounds__(256)
void zero_kernel(uint4* __restrict__ p) {
    p[blockIdx.x * 256 + threadIdx.x] = make_uint4(0u, 0u, 0u, 0u);
}

// ---------------------------------------------------------------- splat ----
// One thread = one (point, batch). Identical fp semantics to passing r4-r12.
__global__ __launch_bounds__(256)
void splat_kernel(const float* __restrict__ V,
                  const float* __restrict__ P,
                  const float* __restrict__ pts,
                  unsigned int* __restrict__ gbm) {
    __shared__ float VP[4][4];
    const int b = blockIdx.y;
    const int t = threadIdx.x;
    if (t < 16) {
        const int i = t >> 2, k = t & 3;
        const float* Pb = P + b * 16;
        const float* Vb = V + b * 16;
        float a = __fmul_rn(Pb[i*4+0], Vb[0*4+k]);
        a = __fmaf_rn(Pb[i*4+1], Vb[1*4+k], a);
        a = __fmaf_rn(Pb[i*4+2], Vb[2*4+k], a);
        a = __fmaf_rn(Pb[i*4+3], Vb[3*4+k], a);
        VP[i][k] = a;
    }
    __syncthreads();
    const int n = blockIdx.x * 256 + t;
    if (n >= NP) return;
    const float4 p = ((const float4*)pts)[n];
    float tp0, tp1, tp3;
    {
        float a = __fmul_rn(p.x, VP[0][0]);
        a = __fmaf_rn(p.y, VP[0][1], a);
        a = __fmaf_rn(p.z, VP[0][2], a);
        a = __fmaf_rn(p.w, VP[0][3], a);
        tp0 = a;
    }
    {
        float a = __fmul_rn(p.x, VP[1][0]);
        a = __fmaf_rn(p.y, VP[1][1], a);
        a = __fmaf_rn(p.z, VP[1][2], a);
        a = __fmaf_rn(p.w, VP[1][3], a);
        tp1 = a;
    }
    {
        float a = __fmul_rn(p.x, VP[3][0]);
        a = __fmaf_rn(p.y, VP[3][1], a);
        a = __fmaf_rn(p.z, VP[3][2], a);
        a = __fmaf_rn(p.w, VP[3][3], a);
        tp3 = a;
    }
    const float w = tp3;
    const float x = (w != 0.f) ? (tp0 / w) : tp0;
    const float y = (w != 0.f) ? (tp1 / w) : tp1;
    const float sxf = rintf(__fmul_rn(__fmul_rn(__fadd_rn(x, 1.f), 0.5f), 512.f));
    const float tmp = __fmul_rn(__fadd_rn(y, 1.f), 0.5f);
    const float syf = rintf(__fmul_rn(__fsub_rn(1.f, tmp), 512.f));
    int sx, sy;
    if (sxf >= 0.f && sxf < 512.f && syf >= 0.f && syf < 512.f) {
        sx = (int)sxf; sy = (int)syf;
    } else {
        sx = 511; sy = 511;   // JAX: flat=-1 wraps to last pixel, not dropped
    }
    atomicOr(&gbm[(b * HH + sy) * WPR + (sx >> 5)], 1u << (sx & 31));
}

// ------------------------------------------------ horizontal dilate (±4) ---
__global__ __launch_bounds__(256)
void hdil_kernel(const unsigned int* __restrict__ in,
                 unsigned int* __restrict__ out) {
    const int idx = blockIdx.x * 256 + threadIdx.x;
    const int wx = idx & (WPR - 1);
    const unsigned int w  = in[idx];
    const unsigned int wl = (wx > 0)       ? in[idx - 1] : 0u;
    const unsigned int wr = (wx < WPR - 1) ? in[idx + 1] : 0u;
    unsigned int hd = w;
#pragma unroll
    for (int k = 1; k <= 4; ++k) {
        hd |= (w << k) | (wl >> (32 - k));
        hd |= (w >> k) | (wr << (32 - k));
    }
    out[idx] = hd;
}

// -------------------------------------------------- vertical dilate (±4) ---
__global__ __launch_bounds__(256)
void vdil_kernel(const unsigned int* __restrict__ in,
                 unsigned int* __restrict__ out) {
    const int idx = blockIdx.x * 256 + threadIdx.x;
    const int b   = idx / (HH * WPR);
    const int rem = idx - b * (HH * WPR);
    const int r   = rem >> 4;          // row
    const int wx  = rem & (WPR - 1);
    const int lo = (r - 4 > 0) ? r - 4 : 0;
    const int hi = (r + 4 < HH - 1) ? r + 4 : HH - 1;
    const unsigned int* base = in + b * HH * WPR + wx;
    unsigned int acc = 0u;
    for (int rr = lo; rr <= hi; ++rr) acc |= base[rr * WPR];
    out[idx] = acc;
}

// --------------------- mask kernel: blur + threshold -> mask BITS ----------
// Exact r10 tile logic (passing, bit-identical fp); emits mask bits via
// global atomicOr instead of 201MB of float stores.
__global__ __launch_bounds__(256)
void mask_kernel(const unsigned int* __restrict__ gdil,
                 unsigned int* __restrict__ mb, GaussW gw) {
    __shared__ float lut[512];

    const int b  = blockIdx.z;
    const int x0 = blockIdx.x * 64;
    const int y0 = blockIdx.y * 64;
    const int tx = threadIdx.x;          // 0..15 -> 4-col group
    const int ty = threadIdx.y;          // 0..15 -> 4-row group
    const int tid = ty * 16 + tx;

    // vertical-blur LUT over 9-bit column patterns (exact ascending-dy fma)
    for (int e = tid; e < 512; e += 256) {
        float acc = 0.f;
#pragma unroll
        for (int dy = 0; dy < 9; ++dy) {
            const float val = ((e >> dy) & 1) ? 255.f : 0.f;
            acc = __fmaf_rn(gw.g[dy], val, acc);
        }
        lut[e] = acc;
    }
    __syncthreads();

    const unsigned int* gb = gdil + b * HH * WPR;
    const int c0 = 4 * tx;

    int rk[12];
    const int rbase = y0 + 4 * ty - 4;
#pragma unroll
    for (int k = 0; k < 12; ++k)
        rk[k] = reflect_idx(rbase + k) * WPR;

    const bool colRef = (x0 == 0 && tx == 0) || (x0 == 448 && tx == 15);

    int mode = 2;                        // 0 all-zero, 1 all-one, 2 mixed
    unsigned int v12[12];

    if (!colRef) {
        const int colA = x0 + c0 - 4;    // >= 0 for non-reflected lanes
        const int wA = colA >> 5;
        const int w2 = (wA + 1 < WPR) ? wA + 1 : WPR - 1;
        const int sh = colA & 31;
        unsigned int e12[12], fOr = 0u, fAnd = 0xFFFu;
#pragma unroll
        for (int k = 0; k < 12; ++k) {
            const unsigned long long cat =
                (((unsigned long long)gb[rk[k] + w2]) << 32) |
                (unsigned long long)gb[rk[k] + wA];
            e12[k] = (unsigned int)(cat >> sh) & 0xFFFu;
            fOr |= e12[k]; fAnd &= e12[k];
        }
        // exact fast paths: all-zero -> blur 0 (not > 100); all-one ->
        // blur ~255 (>> 100); both far from the threshold.
        if (fOr == 0u)           mode = 0;
        else if (fAnd == 0xFFFu) mode = 1;
        else {
#pragma unroll
            for (int j = 0; j < 12; ++j) {
                unsigned int v = 0u;
#pragma unroll
                for (int k = 0; k < 12; ++k)
                    v |= ((e12[k] >> j) & 1u) << k;
                v12[j] = v;
            }
        }
    } else {
        // reflected-column lanes: the 12 cols fold into a single word
        const int wsel = (x0 == 0) ? 0 : WPR - 1;
        unsigned int d[12];
#pragma unroll
        for (int k = 0; k < 12; ++k) d[k] = gb[rk[k] + wsel];
#pragma unroll
        for (int j = 0; j < 12; ++j) {
            const int col = reflect_idx(x0 + c0 - 4 + j);
            const int shc = col & 31;
            unsigned int v = 0u;
#pragma unroll
            for (int k = 0; k < 12; ++k)
                v |= ((d[k] >> shc) & 1u) << k;
            v12[j] = v;
        }
    }

    if (mode == 0) return;               // zero bits: nothing to OR

    const int xq0  = x0 + c0;            // ABSOLUTE column (r13 bug: was c0)
    const int wdst = (b * HH) * WPR + (xq0 >> 5);
    const int bsh  = xq0 & 31;
#pragma unroll
    for (int r = 0; r < 4; ++r) {
        unsigned int nib;
        if (mode == 1) {
            nib = 0xFu;
        } else {
            float f[12];
#pragma unroll
            for (int j = 0; j < 12; ++j)
                f[j] = lut[(v12[j] >> r) & 0x1FFu];
            nib = 0u;
#pragma unroll
            for (int q = 0; q < 4; ++q) {
                float acc = 0.f;
#pragma unroll
                for (int dx = 0; dx < 9; ++dx)
                    acc = __fmaf_rn(gw.g[dx], f[q + dx], acc);
                if (rintf(acc) > 100.f) nib |= (1u << q);
            }
            if (nib == 0u) continue;
        }
        const int yq = y0 + 4 * ty + r;
        atomicOr(&mb[wdst + yq * WPR], nib << bsh);
    }
}

// --------------------- expand kernel: mask bits -> 201MB of floats ---------
// Pure streamer: each thread reads 16 mask bits (L2-resident) and writes
// 64B contiguous x nontemporal. Wave = 4KB contiguous.
__global__ __launch_bounds__(256)
void expand_kernel(const unsigned int* __restrict__ mb,
                   float* __restrict__ out) {
    const int c   = blockIdx.x * 256 + threadIdx.x;   // 0..16383 chunk in plane
    const int y   = c >> 5;
    const int x16 = c & 31;                           // 16-px chunk in row
    const int b   = blockIdx.z;
    const int ch  = blockIdx.y;

    const unsigned int word = mb[(b * HH + y) * WPR + (x16 >> 1)];
    const unsigned int bits = (word >> ((x16 & 1) * 16)) & 0xFFFFu;

    float* o = out + (((size_t)(b * 3 + ch) * HH + y) * WW) + x16 * 16;
#pragma unroll
    for (int v = 0; v < 4; ++v) {
        vfloat4 q;
#pragma unroll
        for (int i = 0; i < 4; ++i)
            q[i] = ((bits >> (4 * v + i)) & 1u) ? 1.f : 0.f;
        __builtin_nontemporal_store(q, (vfloat4*)(o + 4 * v));
    }
}

// ---------------------------------------------------------------- launch ---
extern "C" void kernel_launch(void* const* d_in, const int* in_sizes, int n_in,
                              void* d_out, int out_size, void* d_ws, size_t ws_size,
                              hipStream_t stream) {
    const float* V   = (const float*)d_in[0];
    const float* P   = (const float*)d_in[1];
    const float* pts = (const float*)d_in[2];
    float* out = (float*)d_out;
    unsigned int* buf0 = (unsigned int*)d_ws;     // splat bits -> dilated bits
    unsigned int* buf1 = buf0 + IMG_WORDS;        // h-dilated -> final mask bits

    // Gaussian weights, replicating numpy f64 computation incl. pairwise sum
    const double sigma = 0.3 * ((9 - 1) * 0.5 - 1.0) + 0.8;
    double gd[9];
    for (int i = 0; i < 9; ++i) {
        const double t = ((double)i - 4.0) / sigma;
        gd[i] = exp(-0.5 * (t * t));
    }
    double s = ((gd[0] + gd[1]) + (gd[2] + gd[3])) + ((gd[4] + gd[5]) + (gd[6] + gd[7]));
    s += gd[8];
    GaussW gw;
    for (int i = 0; i < 9; ++i) gw.g[i] = (float)(gd[i] / s);

    zero_kernel<<<IMG_WORDS / 4 / 256, 256, 0, stream>>>((uint4*)buf0);
    splat_kernel<<<dim3((NP + 255) / 256, BB), 256, 0, stream>>>(V, P, pts, buf0);
    hdil_kernel<<<IMG_WORDS / 256, 256, 0, stream>>>(buf0, buf1);
    vdil_kernel<<<IMG_WORDS / 256, 256, 0, stream>>>(buf1, buf0);
    zero_kernel<<<IMG_WORDS / 4 / 256, 256, 0, stream>>>((uint4*)buf1);
    mask_kernel<<<dim3(8, 8, BB), dim3(16, 16), 0, stream>>>(buf0, buf1, gw);
    expand_kernel<<<dim3(64, 3, BB), 256, 0, stream>>>(buf1, out);
}

// Round 15
// 124.400 us; speedup vs baseline: 2.9164x; 2.9164x over previous
//
#include <hip/hip_runtime.h>
#include <math.h>
#include <stdint.h>

#define HH 512
#define WW 512
#define BB 64
#define NP 13860
#define WPR 16                       // 32-bit words per image row
#define IMG_WORDS (BB * HH * WPR)    // 2 MB bit-image for all batches

typedef float vfloat4 __attribute__((ext_vector_type(4)));

struct GaussW { float g[9]; };

__device__ __forceinline__ int reflect_idx(int i) {
    if (i < 0) i = -i;
    if (i > 511) i = 1022 - i;
    return i;
}

// ----------------------------------------------------------------- zero ----
__global__ __launch_bounds__(256)
void zero_kernel(uint4* __restrict__ p) {
    p[blockIdx.x * 256 + threadIdx.x] = make_uint4(0u, 0u, 0u, 0u);
}

// ---------------------------------------------------------------- splat ----
// One thread = one (point, batch). Identical fp semantics to passing r4-r14.
__global__ __launch_bounds__(256)
void splat_kernel(const float* __restrict__ V,
                  const float* __restrict__ P,
                  const float* __restrict__ pts,
                  unsigned int* __restrict__ gbm) {
    __shared__ float VP[4][4];
    const int b = blockIdx.y;
    const int t = threadIdx.x;
    if (t < 16) {
        const int i = t >> 2, k = t & 3;
        const float* Pb = P + b * 16;
        const float* Vb = V + b * 16;
        float a = __fmul_rn(Pb[i*4+0], Vb[0*4+k]);
        a = __fmaf_rn(Pb[i*4+1], Vb[1*4+k], a);
        a = __fmaf_rn(Pb[i*4+2], Vb[2*4+k], a);
        a = __fmaf_rn(Pb[i*4+3], Vb[3*4+k], a);
        VP[i][k] = a;
    }
    __syncthreads();
    const int n = blockIdx.x * 256 + t;
    if (n >= NP) return;
    const float4 p = ((const float4*)pts)[n];
    float tp0, tp1, tp3;
    {
        float a = __fmul_rn(p.x, VP[0][0]);
        a = __fmaf_rn(p.y, VP[0][1], a);
        a = __fmaf_rn(p.z, VP[0][2], a);
        a = __fmaf_rn(p.w, VP[0][3], a);
        tp0 = a;
    }
    {
        float a = __fmul_rn(p.x, VP[1][0]);
        a = __fmaf_rn(p.y, VP[1][1], a);
        a = __fmaf_rn(p.z, VP[1][2], a);
        a = __fmaf_rn(p.w, VP[1][3], a);
        tp1 = a;
    }
    {
        float a = __fmul_rn(p.x, VP[3][0]);
        a = __fmaf_rn(p.y, VP[3][1], a);
        a = __fmaf_rn(p.z, VP[3][2], a);
        a = __fmaf_rn(p.w, VP[3][3], a);
        tp3 = a;
    }
    const float w = tp3;
    const float x = (w != 0.f) ? (tp0 / w) : tp0;
    const float y = (w != 0.f) ? (tp1 / w) : tp1;
    const float sxf = rintf(__fmul_rn(__fmul_rn(__fadd_rn(x, 1.f), 0.5f), 512.f));
    const float tmp = __fmul_rn(__fadd_rn(y, 1.f), 0.5f);
    const float syf = rintf(__fmul_rn(__fsub_rn(1.f, tmp), 512.f));
    int sx, sy;
    if (sxf >= 0.f && sxf < 512.f && syf >= 0.f && syf < 512.f) {
        sx = (int)sxf; sy = (int)syf;
    } else {
        sx = 511; sy = 511;   // JAX: flat=-1 wraps to last pixel, not dropped
    }
    atomicOr(&gbm[(b * HH + sy) * WPR + (sx >> 5)], 1u << (sx & 31));
}

// ------------------------------------------------ horizontal dilate (±4) ---
__global__ __launch_bounds__(256)
void hdil_kernel(const unsigned int* __restrict__ in,
                 unsigned int* __restrict__ out) {
    const int idx = blockIdx.x * 256 + threadIdx.x;
    const int wx = idx & (WPR - 1);
    const unsigned int w  = in[idx];
    const unsigned int wl = (wx > 0)       ? in[idx - 1] : 0u;
    const unsigned int wr = (wx < WPR - 1) ? in[idx + 1] : 0u;
    unsigned int hd = w;
#pragma unroll
    for (int k = 1; k <= 4; ++k) {
        hd |= (w << k) | (wl >> (32 - k));
        hd |= (w >> k) | (wr << (32 - k));
    }
    out[idx] = hd;
}

// -------------------------------------------------- vertical dilate (±4) ---
__global__ __launch_bounds__(256)
void vdil_kernel(const unsigned int* __restrict__ in,
                 unsigned int* __restrict__ out) {
    const int idx = blockIdx.x * 256 + threadIdx.x;
    const int b   = idx / (HH * WPR);
    const int rem = idx - b * (HH * WPR);
    const int r   = rem >> 4;          // row
    const int wx  = rem & (WPR - 1);
    const int lo = (r - 4 > 0) ? r - 4 : 0;
    const int hi = (r + 4 < HH - 1) ? r + 4 : HH - 1;
    const unsigned int* base = in + b * HH * WPR + wx;
    unsigned int acc = 0u;
    for (int rr = lo; rr <= hi; ++rr) acc |= base[rr * WPR];
    out[idx] = acc;
}

// --------------------- mask kernel: blur + threshold -> mask BITS ----------
// NO atomics: each wave assembles full 32-bit words via shfl_xor OR-butterfly
// and stores each (b,row,word) exactly once. r14's atomicOr caused 104MB of
// HBM writeback (cross-XCD line ping-pong) — this removes it.
__global__ __launch_bounds__(256)
void mask_kernel(const unsigned int* __restrict__ gdil,
                 unsigned int* __restrict__ mb, GaussW gw) {
    __shared__ float lut[512];

    const int b  = blockIdx.z;
    const int x0 = blockIdx.x * 64;
    const int y0 = blockIdx.y * 64;
    const int tx = threadIdx.x;          // 0..15 -> 4-col group
    const int ty = threadIdx.y;          // 0..15 -> 4-row group
    const int tid = ty * 16 + tx;

    // vertical-blur LUT over 9-bit column patterns (exact ascending-dy fma)
    for (int e = tid; e < 512; e += 256) {
        float acc = 0.f;
#pragma unroll
        for (int dy = 0; dy < 9; ++dy) {
            const float val = ((e >> dy) & 1) ? 255.f : 0.f;
            acc = __fmaf_rn(gw.g[dy], val, acc);
        }
        lut[e] = acc;
    }
    __syncthreads();

    const unsigned int* gb = gdil + b * HH * WPR;
    const int c0 = 4 * tx;

    int rk[12];
    const int rbase = y0 + 4 * ty - 4;
#pragma unroll
    for (int k = 0; k < 12; ++k)
        rk[k] = reflect_idx(rbase + k) * WPR;

    const bool colRef = (x0 == 0 && tx == 0) || (x0 == 448 && tx == 15);

    int mode = 2;                        // 0 all-zero, 1 all-one, 2 mixed
    unsigned int v12[12];

    if (!colRef) {
        const int colA = x0 + c0 - 4;    // >= 0 for non-reflected lanes
        const int wA = colA >> 5;
        const int w2 = (wA + 1 < WPR) ? wA + 1 : WPR - 1;
        const int sh = colA & 31;
        unsigned int e12[12], fOr = 0u, fAnd = 0xFFFu;
#pragma unroll
        for (int k = 0; k < 12; ++k) {
            const unsigned long long cat =
                (((unsigned long long)gb[rk[k] + w2]) << 32) |
                (unsigned long long)gb[rk[k] + wA];
            e12[k] = (unsigned int)(cat >> sh) & 0xFFFu;
            fOr |= e12[k]; fAnd &= e12[k];
        }
        // exact fast paths: all-zero -> blur 0 (not > 100); all-one ->
        // blur ~255 (>> 100); both far from the threshold.
        if (fOr == 0u)           mode = 0;
        else if (fAnd == 0xFFFu) mode = 1;
        else {
#pragma unroll
            for (int j = 0; j < 12; ++j) {
                unsigned int v = 0u;
#pragma unroll
                for (int k = 0; k < 12; ++k)
                    v |= ((e12[k] >> j) & 1u) << k;
                v12[j] = v;
            }
        }
    } else {
        // reflected-column lanes: the 12 cols fold into a single word
        const int wsel = (x0 == 0) ? 0 : WPR - 1;
        unsigned int d[12];
#pragma unroll
        for (int k = 0; k < 12; ++k) d[k] = gb[rk[k] + wsel];
#pragma unroll
        for (int j = 0; j < 12; ++j) {
            const int col = reflect_idx(x0 + c0 - 4 + j);
            const int shc = col & 31;
            unsigned int v = 0u;
#pragma unroll
            for (int k = 0; k < 12; ++k)
                v |= ((d[k] >> shc) & 1u) << k;
            v12[j] = v;
        }
    }

    // per row: nibble -> wave OR-butterfly over the 8 lanes of each word ->
    // single plain store by the word-owner lane. All lanes participate.
    const int sh4  = 4 * (tx & 7);
    const int wdst = (b * HH) * WPR + (x0 >> 5) + (tx >> 3);
#pragma unroll
    for (int r = 0; r < 4; ++r) {
        unsigned int nib = 0u;
        if (mode == 1) {
            nib = 0xFu;
        } else if (mode == 2) {
            float f[12];
#pragma unroll
            for (int j = 0; j < 12; ++j)
                f[j] = lut[(v12[j] >> r) & 0x1FFu];
#pragma unroll
            for (int q = 0; q < 4; ++q) {
                float acc = 0.f;
#pragma unroll
                for (int dx = 0; dx < 9; ++dx)
                    acc = __fmaf_rn(gw.g[dx], f[q + dx], acc);
                if (rintf(acc) > 100.f) nib |= (1u << q);
            }
        }
        unsigned int v = nib << sh4;
        v |= __shfl_xor(v, 1);
        v |= __shfl_xor(v, 2);
        v |= __shfl_xor(v, 4);
        if ((tx & 7) == 0) {
            const int yq = y0 + 4 * ty + r;
            mb[wdst + yq * WPR] = v;
        }
    }
}

// --------------------- expand kernel: mask bits -> 201MB of floats ---------
// Wave-contiguous streamer: per store instruction, 64 lanes write 64
// consecutive float4s = 1KB contiguous, nontemporal.
__global__ __launch_bounds__(256)
void expand_kernel(const unsigned int* __restrict__ mb,
                   float* __restrict__ out) {
    const int b  = blockIdx.z;
    const int ch = blockIdx.y;
    const unsigned int* mrow = mb + (size_t)b * HH * WPR;
    float* o = out + ((size_t)(b * 3 + ch) * HH) * WW;

#pragma unroll
    for (int v = 0; v < 4; ++v) {
        const int f  = blockIdx.x * 1024 + v * 256 + threadIdx.x; // float4 idx
        const int y  = f >> 7;                    // 128 float4s per row
        const int xq = (f & 127) * 4;             // starting pixel in row
        const unsigned int word = mrow[y * WPR + (xq >> 5)];
        const unsigned int nib  = (word >> (xq & 31)) & 0xFu;
        vfloat4 q;
#pragma unroll
        for (int i = 0; i < 4; ++i)
            q[i] = ((nib >> i) & 1u) ? 1.f : 0.f;
        __builtin_nontemporal_store(q, (vfloat4*)(o + (size_t)f * 4));
    }
}

// ---------------------------------------------------------------- launch ---
extern "C" void kernel_launch(void* const* d_in, const int* in_sizes, int n_in,
                              void* d_out, int out_size, void* d_ws, size_t ws_size,
                              hipStream_t stream) {
    const float* V   = (const float*)d_in[0];
    const float* P   = (const float*)d_in[1];
    const float* pts = (const float*)d_in[2];
    float* out = (float*)d_out;
    unsigned int* buf0 = (unsigned int*)d_ws;     // splat bits -> dilated bits
    unsigned int* buf1 = buf0 + IMG_WORDS;        // h-dilated -> final mask bits

    // Gaussian weights, replicating numpy f64 computation incl. pairwise sum
    const double sigma = 0.3 * ((9 - 1) * 0.5 - 1.0) + 0.8;
    double gd[9];
    for (int i = 0; i < 9; ++i) {
        const double t = ((double)i - 4.0) / sigma;
        gd[i] = exp(-0.5 * (t * t));
    }
    double s = ((gd[0] + gd[1]) + (gd[2] + gd[3])) + ((gd[4] + gd[5]) + (gd[6] + gd[7]));
    s += gd[8];
    GaussW gw;
    for (int i = 0; i < 9; ++i) gw.g[i] = (float)(gd[i] / s);

    zero_kernel<<<IMG_WORDS / 4 / 256, 256, 0, stream>>>((uint4*)buf0);
    splat_kernel<<<dim3((NP + 255) / 256, BB), 256, 0, stream>>>(V, P, pts, buf0);
    hdil_kernel<<<IMG_WORDS / 256, 256, 0, stream>>>(buf0, buf1);
    vdil_kernel<<<IMG_WORDS / 256, 256, 0, stream>>>(buf1, buf0);
    mask_kernel<<<dim3(8, 8, BB), dim3(16, 16), 0, stream>>>(buf0, buf1, gw);
    expand_kernel<<<dim3(64, 3, BB), 256, 0, stream>>>(buf1, out);
}